// Round 1
// baseline (99954.150 us; speedup 1.0000x reference)
//
#include <hip/hip_runtime.h>
#include <hip/hip_bf16.h>
#include <stdint.h>

// ESN: out[t] = tanh(X@W_in^T [t] + W_res @ out[t-1]), T=16384 sequential steps.
// Kernel 1 writes U = X@W_in^T into d_out in place; kernel 2 is a 32-block
// persistent cooperative scan: sparse W_res rows (5% nnz) held in registers,
// state exchanged through LLC with agent-scope atomics + per-block flags.

constexpr int T_N = 16384;
constexpr int R_N = 1024;
constexpr int I_N = 128;

// ---------------------------------------------------------------- kernel 1
// U = X (T,I) @ W_in^T (I,R)  -> (T,R), written into d_out.
constexpr int BT = 64, BR = 64;

__global__ __launch_bounds__(256) void gemm_u_kernel(
    const float* __restrict__ X, const float* __restrict__ Win,
    float* __restrict__ U)
{
    __shared__ float XS[BT][68];   // pad 68: float4-aligned rows, spread banks
    __shared__ float WS[BR][68];
    const int tid = threadIdx.x;
    const int ty = tid >> 4, tx = tid & 15;
    const int t0 = blockIdx.x * BT;
    const int r0 = blockIdx.y * BR;
    float acc[4][4] = {};

    for (int k0 = 0; k0 < I_N; k0 += 64) {
        for (int idx = tid; idx < BT * 16; idx += 256) {
            int row = idx >> 4, c4 = (idx & 15) << 2;
            *reinterpret_cast<float4*>(&XS[row][c4]) =
                *reinterpret_cast<const float4*>(&X[(size_t)(t0 + row) * I_N + k0 + c4]);
        }
        for (int idx = tid; idx < BR * 16; idx += 256) {
            int row = idx >> 4, c4 = (idx & 15) << 2;
            *reinterpret_cast<float4*>(&WS[row][c4]) =
                *reinterpret_cast<const float4*>(&Win[(size_t)(r0 + row) * I_N + k0 + c4]);
        }
        __syncthreads();
#pragma unroll
        for (int k = 0; k < 64; k += 4) {
            float4 a[4], b[4];
#pragma unroll
            for (int i = 0; i < 4; ++i)
                a[i] = *reinterpret_cast<const float4*>(&XS[ty + 16 * i][k]);
#pragma unroll
            for (int jj = 0; jj < 4; ++jj)
                b[jj] = *reinterpret_cast<const float4*>(&WS[tx + 16 * jj][k]);
#pragma unroll
            for (int i = 0; i < 4; ++i)
#pragma unroll
                for (int jj = 0; jj < 4; ++jj)
                    acc[i][jj] += a[i].x * b[jj].x + a[i].y * b[jj].y +
                                  a[i].z * b[jj].z + a[i].w * b[jj].w;
        }
        __syncthreads();
    }
#pragma unroll
    for (int i = 0; i < 4; ++i)
#pragma unroll
        for (int jj = 0; jj < 4; ++jj)
            U[(size_t)(t0 + ty + 16 * i) * R_N + (r0 + tx + 16 * jj)] = acc[i][jj];
}

// ---------------------------------------------------------------- kernel 2
constexpr int GBLK = 32;           // co-resident blocks (<< 256 CUs: safe)
constexpr int B2   = 512;          // threads per block (8 waves)
constexpr int RPB  = R_N / GBLK;   // 32 rows per block
constexpr int TPR  = B2 / RPB;     // 16 threads per row
constexpr int KMAX = 96;           // nnz/row cap: mean 51.2, sigma 7 -> safe
constexpr int NSL  = KMAX / TPR;   // 6 register slots per thread

__global__ __launch_bounds__(512) void esn_scan_kernel(
    const float* __restrict__ Wres, const float* __restrict__ state0,
    float* out, uint32_t* flags)
{
    __shared__ float s_lds[R_N];          // 4 KB  : state s_{t-1}
    __shared__ uint2 ell[RPB][KMAX];      // 24 KB : (col, val-bits) per row
    __shared__ int   cnt[RPB];

    const int tid  = threadIdx.x;
    const int b    = blockIdx.x;
    const int row0 = b * RPB;

    // ---- one-time: extract this block's sparse rows from dense W_res
    if (tid < RPB) cnt[tid] = 0;
    __syncthreads();
    for (int idx = tid; idx < RPB * R_N; idx += B2) {   // coalesced scan
        int r = idx >> 10, c = idx & (R_N - 1);
        float w = Wres[(size_t)(row0 + r) * R_N + c];
        if (w != 0.0f) {
            int slot = atomicAdd(&cnt[r], 1);
            if (slot < KMAX) ell[r][slot] = make_uint2((uint32_t)c, __float_as_uint(w));
        }
    }
    __syncthreads();

    // ---- hoist my slots into registers (branchless dead slots: val=0,col=0)
    const int rloc = tid / TPR;       // 0..31
    const int j    = tid % TPR;       // 0..15
    const int row  = row0 + rloc;
    int   cols[NSL];
    float vals[NSL];
    {
        int myn = cnt[rloc];
#pragma unroll
        for (int k = 0; k < NSL; ++k) {
            int slot = j + k * TPR;
            if (slot < myn) {
                uint2 e = ell[rloc][slot];
                cols[k] = (int)e.x;
                vals[k] = __uint_as_float(e.y);
            } else { cols[k] = 0; vals[k] = 0.0f; }
        }
    }

    for (int i = tid; i < R_N; i += B2) s_lds[i] = state0[i];
    __syncthreads();

    // ---- the sequential scan
    for (int t = 0; t < T_N; ++t) {
        const size_t base = (size_t)t * R_N;

        // u_t for my row (plain load: written by kernel 1, line owned by this
        // block only -- 128B slice per block, no cross-block line sharing)
        float uval = (j == 0) ? out[base + row] : 0.0f;

        float acc = 0.0f;
#pragma unroll
        for (int k = 0; k < NSL; ++k) acc += vals[k] * s_lds[cols[k]];

        acc += __shfl_xor(acc, 1, TPR);
        acc += __shfl_xor(acc, 2, TPR);
        acc += __shfl_xor(acc, 4, TPR);
        acc += __shfl_xor(acc, 8, TPR);

        if (j == 0) {
            float y = tanhf(uval + acc);
            // write-through to LLC so other XCDs can see it
            __hip_atomic_store(&out[base + row], y,
                               __ATOMIC_RELAXED, __HIP_MEMORY_SCOPE_AGENT);
        }
        __threadfence();          // s_waitcnt vmcnt(0): store is at LLC
        __syncthreads();          // whole block's slice published
        if (tid == 0)
            __hip_atomic_store(&flags[b], (uint32_t)(t + 1),
                               __ATOMIC_RELEASE, __HIP_MEMORY_SCOPE_AGENT);
        if (tid < GBLK) {         // lane L polls block L's flag
            while (__hip_atomic_load(&flags[tid], __ATOMIC_ACQUIRE,
                                     __HIP_MEMORY_SCOPE_AGENT) < (uint32_t)(t + 1))
                __builtin_amdgcn_s_sleep(1);
        }
        __syncthreads();

        // reload full state from LLC (cache-bypassing agent loads)
        for (int i = tid; i < R_N; i += B2) {
            uint32_t bits = __hip_atomic_load(
                reinterpret_cast<const uint32_t*>(&out[base + i]),
                __ATOMIC_RELAXED, __HIP_MEMORY_SCOPE_AGENT);
            s_lds[i] = __uint_as_float(bits);
        }
        __syncthreads();
    }
}

// ---------------------------------------------------------------- launcher
extern "C" void kernel_launch(void* const* d_in, const int* in_sizes, int n_in,
                              void* d_out, int out_size, void* d_ws, size_t ws_size,
                              hipStream_t stream)
{
    const float* X      = (const float*)d_in[0];   // (T, I)
    const float* W_in   = (const float*)d_in[1];   // (R, I)
    const float* W_res  = (const float*)d_in[2];   // (R, R)
    const float* state0 = (const float*)d_in[3];   // (R,)
    float* out = (float*)d_out;                    // (T, R)
    uint32_t* flags = (uint32_t*)d_ws;             // GBLK flags

    hipMemsetAsync(d_ws, 0, 256, stream);          // flags start at 0 each launch

    dim3 g1(T_N / BT, R_N / BR);
    gemm_u_kernel<<<g1, 256, 0, stream>>>(X, W_in, out);

    esn_scan_kernel<<<GBLK, B2, 0, stream>>>(W_res, state0, out, flags);
}

// Round 2
// 25712.778 us; speedup vs baseline: 3.8873x; 3.8873x over previous
//
#include <hip/hip_runtime.h>
#include <hip/hip_bf16.h>
#include <stdint.h>

// ESN: out[t] = tanh(U[t] + W_res @ s_{t-1}), T=16384 strictly sequential steps.
// Kernel 1: U = X@W_in^T written into d_out in place.
// Kernel 2: 16-block persistent dataflow scan. Sparse W_res rows (5% nnz) live
// in registers. State exchange: each element published as an 8-byte
// (tag<<32 | value) relaxed agent-scope atomic into a ping-pong buffer in d_ws;
// consumers poll tag >= t. No fences, no flags, one barrier per step.

constexpr int T_N = 16384;
constexpr int R_N = 1024;
constexpr int I_N = 128;

// ---------------------------------------------------------------- kernel 1
constexpr int BT = 64, BR = 64;

__global__ __launch_bounds__(256) void gemm_u_kernel(
    const float* __restrict__ X, const float* __restrict__ Win,
    float* __restrict__ U)
{
    __shared__ float XS[BT][68];
    __shared__ float WS[BR][68];
    const int tid = threadIdx.x;
    const int ty = tid >> 4, tx = tid & 15;
    const int t0 = blockIdx.x * BT;
    const int r0 = blockIdx.y * BR;
    float acc[4][4] = {};

    for (int k0 = 0; k0 < I_N; k0 += 64) {
        for (int idx = tid; idx < BT * 16; idx += 256) {
            int row = idx >> 4, c4 = (idx & 15) << 2;
            *reinterpret_cast<float4*>(&XS[row][c4]) =
                *reinterpret_cast<const float4*>(&X[(size_t)(t0 + row) * I_N + k0 + c4]);
        }
        for (int idx = tid; idx < BR * 16; idx += 256) {
            int row = idx >> 4, c4 = (idx & 15) << 2;
            *reinterpret_cast<float4*>(&WS[row][c4]) =
                *reinterpret_cast<const float4*>(&Win[(size_t)(r0 + row) * I_N + k0 + c4]);
        }
        __syncthreads();
#pragma unroll
        for (int k = 0; k < 64; k += 4) {
            float4 a[4], b[4];
#pragma unroll
            for (int i = 0; i < 4; ++i)
                a[i] = *reinterpret_cast<const float4*>(&XS[ty + 16 * i][k]);
#pragma unroll
            for (int jj = 0; jj < 4; ++jj)
                b[jj] = *reinterpret_cast<const float4*>(&WS[tx + 16 * jj][k]);
#pragma unroll
            for (int i = 0; i < 4; ++i)
#pragma unroll
                for (int jj = 0; jj < 4; ++jj)
                    acc[i][jj] += a[i].x * b[jj].x + a[i].y * b[jj].y +
                                  a[i].z * b[jj].z + a[i].w * b[jj].w;
        }
        __syncthreads();
    }
#pragma unroll
    for (int i = 0; i < 4; ++i)
#pragma unroll
        for (int jj = 0; jj < 4; ++jj)
            U[(size_t)(t0 + ty + 16 * i) * R_N + (r0 + tx + 16 * jj)] = acc[i][jj];
}

// ---------------------------------------------------------------- kernel 2
constexpr int GBLK = 16;           // co-resident blocks, 64 rows each
constexpr int B2   = 512;          // 8 waves
constexpr int RPB  = R_N / GBLK;   // 64 rows per block
constexpr int TPR  = B2 / RPB;     // 8 threads per row
constexpr int KMAX = 96;           // proven sufficient in round 1 (absmax 4e-3)
constexpr int NSL  = KMAX / TPR;   // 12 register slots per thread

__device__ __forceinline__ float fast_tanh(float x) {
    float ax = fabsf(x);
    float e  = __expf(-2.0f * ax);          // v_exp_f32 path, no overflow
    float y  = (1.0f - e) / (1.0f + e);     // in [0,1), ->1 for large ax
    return copysignf(y, x);
}

__global__ __launch_bounds__(512) void esn_scan_kernel(
    const float* __restrict__ Wres, const float* __restrict__ state0,
    float* out, unsigned long long* ws)   // ws: [2][R_N] (tag<<32|bits)
{
    __shared__ float sbuf[2][R_N];        // ping-pong state (8 KB)
    __shared__ uint2 ell[RPB][KMAX];      // 48 KB (col, val-bits)
    __shared__ int   cnt[RPB];

    const int tid  = threadIdx.x;
    const int b    = blockIdx.x;
    const int row0 = b * RPB;

    // ---- one-time: extract this block's sparse rows from dense W_res
    if (tid < RPB) cnt[tid] = 0;
    __syncthreads();
    for (int idx = tid; idx < RPB * R_N; idx += B2) {     // coalesced scan
        int r = idx >> 10, c = idx & (R_N - 1);
        float w = Wres[(size_t)(row0 + r) * R_N + c];
        if (w != 0.0f) {
            int slot = atomicAdd(&cnt[r], 1);
            if (slot < KMAX) ell[r][slot] = make_uint2((uint32_t)c, __float_as_uint(w));
        }
    }
    __syncthreads();

    // ---- hoist my slots into registers (dead slots: col=0, val=0)
    const int rloc = tid / TPR;       // 0..63
    const int j    = tid % TPR;       // 0..7
    const int row  = row0 + rloc;
    int   cols[NSL];
    float vals[NSL];
    {
        int myn = cnt[rloc];
#pragma unroll
        for (int k = 0; k < NSL; ++k) {
            int slot = j + k * TPR;
            if (slot < myn) {
                uint2 e = ell[rloc][slot];
                cols[k] = (int)e.x;
                vals[k] = __uint_as_float(e.y);
            } else { cols[k] = 0; vals[k] = 0.0f; }
        }
    }

    // seed parity-0 buffer with state0
    const int i0 = tid, i1 = tid + B2;
    sbuf[0][i0] = state0[i0];
    sbuf[0][i1] = state0[i1];

    // ---- the sequential scan: one barrier per step, dataflow otherwise
    for (int t = 0; t < T_N; ++t) {
        const int p = t & 1;                 // buffer holding s_{t-1}

        // u_t for my row: issue early, overlaps the poll
        float uval = (j == 0) ? out[(size_t)t * R_N + row] : 0.0f;

        if (t > 0) {
            // s_{t-1} lives at ws parity (t-1)&1 with tag == t
            const unsigned long long* src = ws + (size_t)((t - 1) & 1) * R_N;
            const uint32_t want = (uint32_t)t;
            unsigned long long w0 = 0, w1 = 0;
            bool ok0 = false, ok1 = false;
            do {
                if (!ok0) {
                    w0 = __hip_atomic_load(&src[i0], __ATOMIC_RELAXED,
                                           __HIP_MEMORY_SCOPE_AGENT);
                    ok0 = (uint32_t)(w0 >> 32) >= want;
                }
                if (!ok1) {
                    w1 = __hip_atomic_load(&src[i1], __ATOMIC_RELAXED,
                                           __HIP_MEMORY_SCOPE_AGENT);
                    ok1 = (uint32_t)(w1 >> 32) >= want;
                }
            } while (!(ok0 && ok1));
            sbuf[p][i0] = __uint_as_float((uint32_t)w0);
            sbuf[p][i1] = __uint_as_float((uint32_t)w1);
        }
        __syncthreads();                      // sbuf[p] complete

        float acc = 0.0f;
#pragma unroll
        for (int k = 0; k < NSL; ++k) acc += vals[k] * sbuf[p][cols[k]];

        acc += __shfl_xor(acc, 1, TPR);
        acc += __shfl_xor(acc, 2, TPR);
        acc += __shfl_xor(acc, 4, TPR);

        if (j == 0) {
            float y = fast_tanh(uval + acc);
            out[(size_t)t * R_N + row] = y;   // final answer, fire-and-forget
            unsigned long long pkt =
                ((unsigned long long)(uint32_t)(t + 1) << 32) | __float_as_uint(y);
            __hip_atomic_store(&ws[(size_t)p * R_N + row], pkt,
                               __ATOMIC_RELAXED, __HIP_MEMORY_SCOPE_AGENT);
        }
        // no trailing barrier: next step writes sbuf[p^1], cannot race gathers
    }
}

// ---------------------------------------------------------------- launcher
extern "C" void kernel_launch(void* const* d_in, const int* in_sizes, int n_in,
                              void* d_out, int out_size, void* d_ws, size_t ws_size,
                              hipStream_t stream)
{
    const float* X      = (const float*)d_in[0];   // (T, I)
    const float* W_in   = (const float*)d_in[1];   // (R, I)
    const float* W_res  = (const float*)d_in[2];   // (R, R)
    const float* state0 = (const float*)d_in[3];   // (R,)
    float* out = (float*)d_out;                    // (T, R)
    unsigned long long* ws = (unsigned long long*)d_ws;  // 2*R_N tagged slots

    // tags must start < 1 every launch (harness poisons ws with 0xAA)
    hipMemsetAsync(d_ws, 0, 2 * R_N * sizeof(unsigned long long), stream);

    dim3 g1(T_N / BT, R_N / BR);
    gemm_u_kernel<<<g1, 256, 0, stream>>>(X, W_in, out);

    esn_scan_kernel<<<GBLK, B2, 0, stream>>>(W_res, state0, out, ws);
}